// Round 10
// baseline (339.970 us; speedup 1.0000x reference)
//
#include <hip/hip_runtime.h>

// APG_Linear: out[b] = ((inp[b] @ U) @ W_b) @ V + bias
//   B=131072, IN=128, OUT=128, RANK=32, all f32. Memory-bound (671 MB, ~102-107 us floor).
// R9 = R4 (129.9 us) + register diet + occupancy bump (NO algorithmic change):
//   - No shadow prefetch buffers: x0/x1 refilled in place right after step 1
//     consumes them; w4[4] refilled in place right after step 2 consumes it
//     (pattern validated in R8). Cuts ~20 live VGPRs.
//   - __launch_bounds__(256,4): cap VGPR at 128 -> 4 waves/SIMD (R4 at
//     ~135-150 VGPR sat in the 2-waves/SIMD band per m69's 64/128/256 steps).
//   - Step 3 stays f32 V + readlane (R6/R7 showed f16-V costs ~4 us).
// History: R5-R8 all ADDED state and regressed; this round only removes it.

constexpr int RANK  = 32;
constexpr int BLOCK = 256;            // 4 waves/block
constexpr int WPB   = BLOCK / 64;
constexpr int GRID  = 1024;           // 4 blocks/CU at 4 waves/SIMD
constexpr int NWAVES = GRID * WPB;    // 4096 waves -> 32 rows/wave at B=131072

typedef int i2_t __attribute__((ext_vector_type(2)));

__device__ __forceinline__ float bcast(float v, int srclane) {
    return __uint_as_float(__builtin_amdgcn_readlane(__float_as_uint(v), srclane));
}

// --- VALU-pipe butterfly stages (keep these OFF the LDS pipe) ---
__device__ __forceinline__ float red_xor8(float v) {
#if __has_builtin(__builtin_amdgcn_update_dpp)
    int m = __builtin_amdgcn_update_dpp(0, __float_as_int(v), 0x128, 0xf, 0xf, true);
    return v + __int_as_float(m);
#else
    return v + __shfl_xor(v, 8, 64);
#endif
}
__device__ __forceinline__ float red_xor16(float v) {
#if __has_builtin(__builtin_amdgcn_permlane16_swap)
    i2_t r = __builtin_amdgcn_permlane16_swap(__float_as_int(v), __float_as_int(v),
                                              false, false);
    return __int_as_float(r.x) + __int_as_float(r.y);
#else
    return v + __shfl_xor(v, 16, 64);
#endif
}
__device__ __forceinline__ float red_xor32(float v) {
#if __has_builtin(__builtin_amdgcn_permlane32_swap)
    i2_t r = __builtin_amdgcn_permlane32_swap(__float_as_int(v), __float_as_int(v),
                                              false, false);
    return __int_as_float(r.x) + __int_as_float(r.y);
#else
    return v + __shfl_xor(v, 32, 64);
#endif
}
__device__ __forceinline__ float red_g(float v) {
    return red_xor32(red_xor16(red_xor8(v)));
}

__global__ __launch_bounds__(BLOCK, 4)   // VGPR <= 128 -> 4 waves/SIMD
void apg_linear_kernel(const float* __restrict__ inp,
                       const float* __restrict__ gw,
                       const float* __restrict__ U,
                       const float* __restrict__ V,
                       const float* __restrict__ bias,
                       float* __restrict__ out,
                       int nrows)
{
    __shared__ float4 u4s[1024];        // U staged: 128x32 f32 = 16 KiB
    __shared__ float  hbuf[WPB][RANK];  // per-wave h park (128 B each)

    const int tid  = threadIdx.x;
    const int lane = tid & 63;
    const int wid  = tid >> 6;
    const int g    = lane >> 3;         // 0..7

    // ---- stage U into LDS (flat float4 layout: u4s[f] = U[4f..4f+3]) ----
    #pragma unroll
    for (int j = 0; j < 4; ++j)
        u4s[j * BLOCK + tid] = reinterpret_cast<const float4*>(U)[j * BLOCK + tid];
    __syncthreads();

    // ---- V and bias in registers: lane owns output cols {2*lane, 2*lane+1} ----
    float2 v2[RANK];
    #pragma unroll
    for (int r = 0; r < RANK; ++r)
        v2[r] = reinterpret_cast<const float2*>(V + r * 128)[lane];
    const float2 b2 = reinterpret_cast<const float2*>(bias)[lane];

    float* hw = hbuf[wid];

    const int wave0 = blockIdx.x * WPB + wid;
    const int iters = (nrows + NWAVES - 1) / NWAVES;   // 32 at B=131072

    int row = wave0;
    // ---- initial loads (single buffer set; refilled in place each iter) ----
    float x0 = inp[row * 128 + lane];
    float x1 = inp[row * 128 + 64 + lane];
    float4 w4[4];
    {
        const float4* wp = reinterpret_cast<const float4*>(gw) + row * 256;
        #pragma unroll
        for (int t = 0; t < 4; ++t) w4[t] = wp[t * 64 + lane];
    }

    for (int it = 0; it < iters; ++it) {
        // clamped next row (branch-free; last iter redundantly reloads)
        const int nrow = (row + NWAVES < nrows) ? row + NWAVES : row;

        // ---- step 1: h = inp_row @ U (last consumer of x0/x1) -----------
        float h1a[4] = {0.f, 0.f, 0.f, 0.f};
        #pragma unroll
        for (int t = 0; t < 16; ++t) {
            const float xs = (t < 8) ? x0 : x1;            // t is constant
            const float xi = __shfl(xs, (t & 7) * 8 + g, 64);
            const float4 u = u4s[t * 64 + lane];
            h1a[0] = fmaf(xi, u.x, h1a[0]);
            h1a[1] = fmaf(xi, u.y, h1a[1]);
            h1a[2] = fmaf(xi, u.z, h1a[2]);
            h1a[3] = fmaf(xi, u.w, h1a[3]);
        }

        // ---- x refill for next row (x0/x1 now dead) ----------------------
        x0 = inp[nrow * 128 + lane];
        x1 = inp[nrow * 128 + 64 + lane];

        #pragma unroll
        for (int k = 0; k < 4; ++k) h1a[k] = red_g(h1a[k]);   // VALU butterfly
        // park h in per-wave LDS (lane group c holds h[4c..4c+3])
        if (lane < 8)
            reinterpret_cast<float4*>(hw)[lane] =
                make_float4(h1a[0], h1a[1], h1a[2], h1a[3]);

        // ---- step 2: h2 = h @ W_b (last consumer of w4) ------------------
        float h2a[4] = {0.f, 0.f, 0.f, 0.f};
        #pragma unroll
        for (int t = 0; t < 4; ++t) {
            const float hi = hw[t * 8 + g];                // broadcast read
            h2a[0] = fmaf(hi, w4[t].x, h2a[0]);
            h2a[1] = fmaf(hi, w4[t].y, h2a[1]);
            h2a[2] = fmaf(hi, w4[t].z, h2a[2]);
            h2a[3] = fmaf(hi, w4[t].w, h2a[3]);
        }

        // ---- W refill for next row (w4 now dead) -------------------------
        {
            const float4* wp = reinterpret_cast<const float4*>(gw) + nrow * 256;
            #pragma unroll
            for (int t = 0; t < 4; ++t) w4[t] = wp[t * 64 + lane];
        }

        #pragma unroll
        for (int k = 0; k < 4; ++k) h2a[k] = red_g(h2a[k]);   // VALU butterfly

        // ---- step 3: out_row = h2 @ V + bias (readlane broadcasts) -------
        float o0 = b2.x, o1 = b2.y;
        #pragma unroll
        for (int r = 0; r < RANK; ++r) {
            const float h2r = bcast(h2a[r & 3], r >> 2);
            o0 = fmaf(h2r, v2[r].x, o0);
            o1 = fmaf(h2r, v2[r].y, o1);
        }
        reinterpret_cast<float2*>(out)[row * 64 + lane] = make_float2(o0, o1);

        row = nrow;
    }
}

extern "C" void kernel_launch(void* const* d_in, const int* in_sizes, int n_in,
                              void* d_out, int out_size, void* d_ws, size_t ws_size,
                              hipStream_t stream)
{
    const float* inp  = (const float*)d_in[0];
    const float* gw   = (const float*)d_in[1];
    const float* U    = (const float*)d_in[2];
    const float* V    = (const float*)d_in[3];
    const float* bias = (const float*)d_in[4];
    float* out = (float*)d_out;
    const int nrows = in_sizes[0] / 128;   // B = 131072

    apg_linear_kernel<<<GRID, BLOCK, 0, stream>>>(inp, gw, U, V, bias, out, nrows);
}

// Round 11
// 146.276 us; speedup vs baseline: 2.3242x; 2.3242x over previous
//
#include <hip/hip_runtime.h>

// APG_Linear: out[b] = ((inp[b] @ U) @ W_b) @ V + bias
//   B=131072, IN=128, OUT=128, RANK=32, all f32. Memory-bound (671 MB, ~102-107 us floor).
// R10 = R4 (129.9 us) + f16-dot2 on the two SHARED-matrix steps.
// KEY LEARNING (R9): this toolchain's __launch_bounds__(256,arg) caps VGPR at
// ~256/arg: (256,3)->84, (256,4)->64 observed. So (256,2)->128, and R4 (live
// ~130) sat AT the cliff; R6/R7/R8's "regressions" were all spills, not their
// nominal changes. This round SHRINKS state:
//   - V as f16 pairs + v_dot2 step 3 (32 regs, was 64; ~100 cy, was 190).
//     (Numerics proven on HW in R7: absmax 0.0156.)
//   - U as f16 i-pairs in LDS (8 KB, XOR-swizzled) + packed x broadcast:
//     step 1 = 8 bpermute + 8 ds_read_b128 + 32 dot2 (was 16+16+64 fma).
//   - W path, step 2, butterflies, accumulators stay f32. R4 skeleton kept:
//     shadow prefetch, (256,2), GRID 1024.
// Live regs ~100 < 128 cap; VALU/row ~400 cy (was ~508); LDS ~25 ops (was 41).

constexpr int RANK  = 32;
constexpr int BLOCK = 256;            // 4 waves/block
constexpr int WPB   = BLOCK / 64;
constexpr int GRID  = 1024;
constexpr int NWAVES = GRID * WPB;    // 4096 waves -> 32 rows/wave at B=131072

typedef int    i2_t __attribute__((ext_vector_type(2)));
typedef __fp16 h2_t __attribute__((ext_vector_type(2)));

// --- VALU-pipe butterfly stages (keep these OFF the LDS pipe) ---
__device__ __forceinline__ float red_xor8(float v) {
#if __has_builtin(__builtin_amdgcn_update_dpp)
    int m = __builtin_amdgcn_update_dpp(0, __float_as_int(v), 0x128, 0xf, 0xf, true);
    return v + __int_as_float(m);
#else
    return v + __shfl_xor(v, 8, 64);
#endif
}
__device__ __forceinline__ float red_xor16(float v) {
#if __has_builtin(__builtin_amdgcn_permlane16_swap)
    i2_t r = __builtin_amdgcn_permlane16_swap(__float_as_int(v), __float_as_int(v),
                                              false, false);
    return __int_as_float(r.x) + __int_as_float(r.y);
#else
    return v + __shfl_xor(v, 16, 64);
#endif
}
__device__ __forceinline__ float red_xor32(float v) {
#if __has_builtin(__builtin_amdgcn_permlane32_swap)
    i2_t r = __builtin_amdgcn_permlane32_swap(__float_as_int(v), __float_as_int(v),
                                              false, false);
    return __int_as_float(r.x) + __int_as_float(r.y);
#else
    return v + __shfl_xor(v, 32, 64);
#endif
}
__device__ __forceinline__ float red_g(float v) {
    return red_xor32(red_xor16(red_xor8(v)));
}

__device__ __forceinline__ int pack_h2(float a, float b) {
    auto p = __builtin_amdgcn_cvt_pkrtz(a, b);   // (a -> lo, b -> hi)
    int i; __builtin_memcpy(&i, &p, 4);
    return i;
}
__device__ __forceinline__ h2_t as_h2(int i) {
    h2_t r; __builtin_memcpy(&r, &i, 4);
    return r;
}
__device__ __forceinline__ h2_t rl_h2(int packed, int srclane) {
    return as_h2(__builtin_amdgcn_readlane(packed, srclane));
}

__global__ __launch_bounds__(BLOCK, 2)   // empirical cap ~128 VGPR on this toolchain
void apg_linear_kernel(const float* __restrict__ inp,
                       const float* __restrict__ gw,
                       const float* __restrict__ U,
                       const float* __restrict__ V,
                       const float* __restrict__ bias,
                       float* __restrict__ out,
                       int nrows)
{
    // U staged as f16 i-pairs: u2s[i2][jblk^ (i2&7)][j&3], i2 in [0,64), j in [0,32)
    __shared__ int   u2s[2048];         // 8 KiB
    __shared__ float hbuf[WPB][RANK];   // per-wave h park (128 B each)

    const int tid  = threadIdx.x;
    const int lane = tid & 63;
    const int wid  = tid >> 6;
    const int g    = lane >> 3;         // 0..7 (i-pair group)
    const int c    = lane & 7;          // 0..7 (column block: cols 4c..4c+3)

    // ---- stage U into LDS as packed f16 pairs, XOR-swizzled j-blocks ----
    for (int e = tid; e < 2048; e += BLOCK) {
        const int i2 = e >> 5, j = e & 31;
        const float a = U[(2 * i2) * 32 + j];
        const float b = U[(2 * i2 + 1) * 32 + j];
        const int blk = (j >> 2) ^ (i2 & 7);
        u2s[i2 * 32 + blk * 4 + (j & 3)] = pack_h2(a, b);
    }
    __syncthreads();

    // ---- V packed as f16 r-pairs: lane owns out cols j0=2*lane, j1=2*lane+1
    h2_t v2a[16], v2b[16];
    #pragma unroll
    for (int s = 0; s < 16; ++s) {
        const float2 r0 = reinterpret_cast<const float2*>(V + (2*s)     * 128)[lane];
        const float2 r1 = reinterpret_cast<const float2*>(V + (2*s + 1) * 128)[lane];
        v2a[s] = h2_t{(__fp16)r0.x, (__fp16)r1.x};
        v2b[s] = h2_t{(__fp16)r0.y, (__fp16)r1.y};
    }
    const float2 b2 = reinterpret_cast<const float2*>(bias)[lane];

    float* hw = hbuf[wid];

    const int wave0 = blockIdx.x * WPB + wid;
    const int iters = (nrows + NWAVES - 1) / NWAVES;   // 32 at B=131072

    int row = wave0;
    // ---- prefetch row 0 (R4 shadow-buffer pattern) ----
    int    xpkn = 0;
    float4 w4n[4] = {};
    if (row < nrows) {
        const float2 xv = reinterpret_cast<const float2*>(inp + row * 128)[lane];
        xpkn = pack_h2(xv.x, xv.y);                     // pair i2 = lane
        const float4* wp = reinterpret_cast<const float4*>(gw) + row * 256;
        #pragma unroll
        for (int t = 0; t < 4; ++t) w4n[t] = wp[t * 64 + lane];
    }

    for (int it = 0; it < iters; ++it) {
        if (row >= nrows) break;
        const int xpk = xpkn;
        float4 w4[4];
        #pragma unroll
        for (int t = 0; t < 4; ++t) w4[t] = w4n[t];

        // ---- prefetch next row (overlaps with compute below) ----
        const int nrow = row + NWAVES;
        if (it + 1 < iters && nrow < nrows) {
            const float2 xv = reinterpret_cast<const float2*>(inp + nrow * 128)[lane];
            xpkn = pack_h2(xv.x, xv.y);
            const float4* wp = reinterpret_cast<const float4*>(gw) + nrow * 256;
            #pragma unroll
            for (int t = 0; t < 4; ++t) w4n[t] = wp[t * 64 + lane];
        }

        // ---- step 1: h = inp_row @ U via f16 dot2 ------------------------
        // lane accumulates h[4c..4c+3] over i-pairs i2 = t*8+g, t=0..7
        float h1a[4] = {0.f, 0.f, 0.f, 0.f};
        #pragma unroll
        for (int t = 0; t < 8; ++t) {
            const h2_t xp = as_h2(__shfl(xpk, t * 8 + g, 64));   // (x[2i2],x[2i2+1])
            const int4 uq = *reinterpret_cast<const int4*>(
                &u2s[(t * 8 + g) * 32 + (c ^ g) * 4]);           // cols 4c..4c+3
            h1a[0] = __builtin_amdgcn_fdot2(xp, as_h2(uq.x), h1a[0], false);
            h1a[1] = __builtin_amdgcn_fdot2(xp, as_h2(uq.y), h1a[1], false);
            h1a[2] = __builtin_amdgcn_fdot2(xp, as_h2(uq.z), h1a[2], false);
            h1a[3] = __builtin_amdgcn_fdot2(xp, as_h2(uq.w), h1a[3], false);
        }
        #pragma unroll
        for (int k = 0; k < 4; ++k) h1a[k] = red_g(h1a[k]);   // VALU butterfly
        // park h in per-wave LDS (lane group c holds h[4c..4c+3])
        if (lane < 8)
            reinterpret_cast<float4*>(hw)[lane] =
                make_float4(h1a[0], h1a[1], h1a[2], h1a[3]);

        // ---- step 2: h2 = h @ W_b (f32, W is the HBM payload) ------------
        float h2a[4] = {0.f, 0.f, 0.f, 0.f};
        #pragma unroll
        for (int t = 0; t < 4; ++t) {
            const float hi = hw[t * 8 + g];                // broadcast read
            h2a[0] = fmaf(hi, w4[t].x, h2a[0]);
            h2a[1] = fmaf(hi, w4[t].y, h2a[1]);
            h2a[2] = fmaf(hi, w4[t].z, h2a[2]);
            h2a[3] = fmaf(hi, w4[t].w, h2a[3]);
        }
        #pragma unroll
        for (int k = 0; k < 4; ++k) h2a[k] = red_g(h2a[k]);   // VALU butterfly

        // ---- step 3: out_row = h2 @ V + bias (f16 dot2; proven in R7) ----
        float o0 = b2.x, o1 = b2.y;
        const int h2p0 = pack_h2(h2a[0], h2a[1]);  // (h2[4c],   h2[4c+1]) @ lane c
        const int h2p1 = pack_h2(h2a[2], h2a[3]);  // (h2[4c+2], h2[4c+3]) @ lane c
        #pragma unroll
        for (int cc = 0; cc < 8; ++cc) {
            const h2_t p0 = rl_h2(h2p0, cc);       // r-pair s = 2cc
            const h2_t p1 = rl_h2(h2p1, cc);       // r-pair s = 2cc+1
            o0 = __builtin_amdgcn_fdot2(p0, v2a[2*cc],     o0, false);
            o1 = __builtin_amdgcn_fdot2(p0, v2b[2*cc],     o1, false);
            o0 = __builtin_amdgcn_fdot2(p1, v2a[2*cc + 1], o0, false);
            o1 = __builtin_amdgcn_fdot2(p1, v2b[2*cc + 1], o1, false);
        }
        reinterpret_cast<float2*>(out)[row * 64 + lane] = make_float2(o0, o1);

        row = nrow;
    }
}

extern "C" void kernel_launch(void* const* d_in, const int* in_sizes, int n_in,
                              void* d_out, int out_size, void* d_ws, size_t ws_size,
                              hipStream_t stream)
{
    const float* inp  = (const float*)d_in[0];
    const float* gw   = (const float*)d_in[1];
    const float* U    = (const float*)d_in[2];
    const float* V    = (const float*)d_in[3];
    const float* bias = (const float*)d_in[4];
    float* out = (float*)d_out;
    const int nrows = in_sizes[0] / 128;   // B = 131072

    apg_linear_kernel<<<GRID, BLOCK, 0, stream>>>(inp, gw, U, V, bias, out, nrows);
}

// Round 12
// 134.858 us; speedup vs baseline: 2.5209x; 1.0847x over previous
//
#include <hip/hip_runtime.h>

// APG_Linear: out[b] = ((inp[b] @ U) @ W_b) @ V + bias
//   B=131072, IN=128, OUT=128, RANK=32, all f32. Memory-bound (671 MB, ~102-107 us floor).
// R11 = R9's register diet at the CORRECT cap — the untested cell:
//   {in-place refill} x {(256,2) -> cap ~128}.
//   - R9 proved (256,4) caps VGPR at 64 (empirical cap ~256/arg: 84@3, 64@4)
//     -> its 340 us was pure spill, not the diet.
//   - R4 (shadow buffers, live ~130-150 @ cap 128) = 129.9 us best, sitting
//     AT the cliff with only 2 waves/SIMD.
//   - This diet (x refilled right after step 1, w4 right after step 2; no
//     shadow copies) has live set ~105-120 -> no spill, 4 waves/SIMD:
//     2x TLP; in-flight latency cover 4 x ~300cy = 1200 > ~900cy HBM.
//   - All-f32 (fdot2 path measured slower in R6/R7/R10: 141-146 us; dead).

constexpr int RANK  = 32;
constexpr int BLOCK = 256;            // 4 waves/block
constexpr int WPB   = BLOCK / 64;
constexpr int GRID  = 1024;
constexpr int NWAVES = GRID * WPB;    // 4096 waves -> 32 rows/wave at B=131072

typedef int i2_t __attribute__((ext_vector_type(2)));

__device__ __forceinline__ float bcast(float v, int srclane) {
    return __uint_as_float(__builtin_amdgcn_readlane(__float_as_uint(v), srclane));
}

// --- VALU-pipe butterfly stages (keep these OFF the LDS pipe) ---
__device__ __forceinline__ float red_xor8(float v) {
#if __has_builtin(__builtin_amdgcn_update_dpp)
    int m = __builtin_amdgcn_update_dpp(0, __float_as_int(v), 0x128, 0xf, 0xf, true);
    return v + __int_as_float(m);
#else
    return v + __shfl_xor(v, 8, 64);
#endif
}
__device__ __forceinline__ float red_xor16(float v) {
#if __has_builtin(__builtin_amdgcn_permlane16_swap)
    i2_t r = __builtin_amdgcn_permlane16_swap(__float_as_int(v), __float_as_int(v),
                                              false, false);
    return __int_as_float(r.x) + __int_as_float(r.y);
#else
    return v + __shfl_xor(v, 16, 64);
#endif
}
__device__ __forceinline__ float red_xor32(float v) {
#if __has_builtin(__builtin_amdgcn_permlane32_swap)
    i2_t r = __builtin_amdgcn_permlane32_swap(__float_as_int(v), __float_as_int(v),
                                              false, false);
    return __int_as_float(r.x) + __int_as_float(r.y);
#else
    return v + __shfl_xor(v, 32, 64);
#endif
}
__device__ __forceinline__ float red_g(float v) {
    return red_xor32(red_xor16(red_xor8(v)));
}

__global__ __launch_bounds__(BLOCK, 2)   // cap ~128 VGPR; diet keeps live ~110
void apg_linear_kernel(const float* __restrict__ inp,
                       const float* __restrict__ gw,
                       const float* __restrict__ U,
                       const float* __restrict__ V,
                       const float* __restrict__ bias,
                       float* __restrict__ out,
                       int nrows)
{
    __shared__ float4 u4s[1024];        // U staged: 128x32 f32 = 16 KiB
    __shared__ float  hbuf[WPB][RANK];  // per-wave h park (128 B each)

    const int tid  = threadIdx.x;
    const int lane = tid & 63;
    const int wid  = tid >> 6;
    const int g    = lane >> 3;         // 0..7

    // ---- stage U into LDS (flat float4 layout: u4s[f] = U[4f..4f+3]) ----
    #pragma unroll
    for (int j = 0; j < 4; ++j)
        u4s[j * BLOCK + tid] = reinterpret_cast<const float4*>(U)[j * BLOCK + tid];
    __syncthreads();

    // ---- V and bias in registers: lane owns output cols {2*lane, 2*lane+1} ----
    float2 v2[RANK];
    #pragma unroll
    for (int r = 0; r < RANK; ++r)
        v2[r] = reinterpret_cast<const float2*>(V + r * 128)[lane];
    const float2 b2 = reinterpret_cast<const float2*>(bias)[lane];

    float* hw = hbuf[wid];

    const int wave0 = blockIdx.x * WPB + wid;
    const int iters = (nrows + NWAVES - 1) / NWAVES;   // 32 at B=131072

    int row = wave0;
    // ---- initial loads (single buffer set; refilled in place each iter) ----
    float x0 = inp[row * 128 + lane];
    float x1 = inp[row * 128 + 64 + lane];
    float4 w4[4];
    {
        const float4* wp = reinterpret_cast<const float4*>(gw) + row * 256;
        #pragma unroll
        for (int t = 0; t < 4; ++t) w4[t] = wp[t * 64 + lane];
    }

    for (int it = 0; it < iters; ++it) {
        // clamped next row (branch-free; last iter redundantly reloads)
        const int nrow = (row + NWAVES < nrows) ? row + NWAVES : row;

        // ---- step 1: h = inp_row @ U (last consumer of x0/x1) -----------
        float h1a[4] = {0.f, 0.f, 0.f, 0.f};
        #pragma unroll
        for (int t = 0; t < 16; ++t) {
            const float xs = (t < 8) ? x0 : x1;            // t is constant
            const float xi = __shfl(xs, (t & 7) * 8 + g, 64);
            const float4 u = u4s[t * 64 + lane];
            h1a[0] = fmaf(xi, u.x, h1a[0]);
            h1a[1] = fmaf(xi, u.y, h1a[1]);
            h1a[2] = fmaf(xi, u.z, h1a[2]);
            h1a[3] = fmaf(xi, u.w, h1a[3]);
        }

        // ---- x refill for next row (x0/x1 now dead) ----------------------
        x0 = inp[nrow * 128 + lane];
        x1 = inp[nrow * 128 + 64 + lane];

        #pragma unroll
        for (int k = 0; k < 4; ++k) h1a[k] = red_g(h1a[k]);   // VALU butterfly
        // park h in per-wave LDS (lane group c holds h[4c..4c+3])
        if (lane < 8)
            reinterpret_cast<float4*>(hw)[lane] =
                make_float4(h1a[0], h1a[1], h1a[2], h1a[3]);

        // ---- step 2: h2 = h @ W_b (last consumer of w4) ------------------
        float h2a[4] = {0.f, 0.f, 0.f, 0.f};
        #pragma unroll
        for (int t = 0; t < 4; ++t) {
            const float hi = hw[t * 8 + g];                // broadcast read
            h2a[0] = fmaf(hi, w4[t].x, h2a[0]);
            h2a[1] = fmaf(hi, w4[t].y, h2a[1]);
            h2a[2] = fmaf(hi, w4[t].z, h2a[2]);
            h2a[3] = fmaf(hi, w4[t].w, h2a[3]);
        }

        // ---- W refill for next row (w4 now dead) -------------------------
        {
            const float4* wp = reinterpret_cast<const float4*>(gw) + nrow * 256;
            #pragma unroll
            for (int t = 0; t < 4; ++t) w4[t] = wp[t * 64 + lane];
        }

        #pragma unroll
        for (int k = 0; k < 4; ++k) h2a[k] = red_g(h2a[k]);   // VALU butterfly

        // ---- step 3: out_row = h2 @ V + bias (readlane broadcasts) -------
        float o0 = b2.x, o1 = b2.y;
        #pragma unroll
        for (int r = 0; r < RANK; ++r) {
            const float h2r = bcast(h2a[r & 3], r >> 2);
            o0 = fmaf(h2r, v2[r].x, o0);
            o1 = fmaf(h2r, v2[r].y, o1);
        }
        reinterpret_cast<float2*>(out)[row * 64 + lane] = make_float2(o0, o1);

        row = nrow;
    }
}

extern "C" void kernel_launch(void* const* d_in, const int* in_sizes, int n_in,
                              void* d_out, int out_size, void* d_ws, size_t ws_size,
                              hipStream_t stream)
{
    const float* inp  = (const float*)d_in[0];
    const float* gw   = (const float*)d_in[1];
    const float* U    = (const float*)d_in[2];
    const float* V    = (const float*)d_in[3];
    const float* bias = (const float*)d_in[4];
    float* out = (float*)d_out;
    const int nrows = in_sizes[0] / 128;   // B = 131072

    apg_linear_kernel<<<GRID, BLOCK, 0, stream>>>(inp, gw, U, V, bias, out, nrows);
}

// Round 13
// 131.235 us; speedup vs baseline: 2.5905x; 1.0276x over previous
//
#include <hip/hip_runtime.h>

// APG_Linear: out[b] = ((inp[b] @ U) @ W_b) @ V + bias
//   B=131072, IN=128, OUT=128, RANK=32, all f32. Memory-bound (671 MB, ~102-107 us floor).
// R12 = R4 (129.9 us, session best) + ONE change: V packed as bf16 pairs in
// 32 u32 regs (was 64 f32 regs), unpacked with pure bit-ops (<<16 / &hi-mask)
// on the f32 FMA pipe — NOT the f16 fdot2 ALU path (that lost: R6/R7/R10).
// Why: R4's live set ~135-145 vs cap 128 ((256,2); empirical cap=256/arg) ->
// mild spill or 2 waves/SIMD. -32 regs -> live ~110: no spill, 4 waves/SIMD
// at full R4 prefetch distance. R8/R9/R11 proved distance > occupancy;
// this keeps distance AND gains occupancy.
// Session facts: shadow prefetch best (R4); in-place refill -5us (R11);
// pair-processing -7us (R8); fdot2 -11us (R10); spills catastrophic (R9).

constexpr int RANK  = 32;
constexpr int BLOCK = 256;            // 4 waves/block
constexpr int WPB   = BLOCK / 64;
constexpr int GRID  = 1024;           // 4 blocks/CU resident, zero tail
constexpr int NWAVES = GRID * WPB;    // 4096 waves -> 32 rows/wave at B=131072

typedef int i2_t __attribute__((ext_vector_type(2)));

__device__ __forceinline__ float bcast(float v, int srclane) {
    return __uint_as_float(__builtin_amdgcn_readlane(__float_as_uint(v), srclane));
}

// --- VALU-pipe butterfly stages (keep these OFF the LDS pipe) ---
__device__ __forceinline__ float red_xor8(float v) {
#if __has_builtin(__builtin_amdgcn_update_dpp)
    int m = __builtin_amdgcn_update_dpp(0, __float_as_int(v), 0x128, 0xf, 0xf, true);
    return v + __int_as_float(m);
#else
    return v + __shfl_xor(v, 8, 64);
#endif
}
__device__ __forceinline__ float red_xor16(float v) {
#if __has_builtin(__builtin_amdgcn_permlane16_swap)
    i2_t r = __builtin_amdgcn_permlane16_swap(__float_as_int(v), __float_as_int(v),
                                              false, false);
    return __int_as_float(r.x) + __int_as_float(r.y);
#else
    return v + __shfl_xor(v, 16, 64);
#endif
}
__device__ __forceinline__ float red_xor32(float v) {
#if __has_builtin(__builtin_amdgcn_permlane32_swap)
    i2_t r = __builtin_amdgcn_permlane32_swap(__float_as_int(v), __float_as_int(v),
                                              false, false);
    return __int_as_float(r.x) + __int_as_float(r.y);
#else
    return v + __shfl_xor(v, 32, 64);
#endif
}
__device__ __forceinline__ float red_g(float v) {
    return red_xor32(red_xor16(red_xor8(v)));
}

__device__ __forceinline__ unsigned bf16_rne(float f) {   // round-to-nearest-even
    const unsigned u = __float_as_uint(f);
    return (u + 0x7fffu + ((u >> 16) & 1u)) >> 16;
}

__global__ __launch_bounds__(BLOCK, 2)   // cap ~128; live ~110 -> no spill
void apg_linear_kernel(const float* __restrict__ inp,
                       const float* __restrict__ gw,
                       const float* __restrict__ U,
                       const float* __restrict__ V,
                       const float* __restrict__ bias,
                       float* __restrict__ out,
                       int nrows)
{
    __shared__ float4 u4s[1024];        // U staged: 128x32 f32 = 16 KiB
    __shared__ float  hbuf[WPB][RANK];  // per-wave h park (128 B each)

    const int tid  = threadIdx.x;
    const int lane = tid & 63;
    const int wid  = tid >> 6;
    const int g    = lane >> 3;         // 0..7

    // ---- stage U into LDS (flat float4 layout: u4s[f] = U[4f..4f+3]) ----
    #pragma unroll
    for (int j = 0; j < 4; ++j)
        u4s[j * BLOCK + tid] = reinterpret_cast<const float4*>(U)[j * BLOCK + tid];
    __syncthreads();

    // ---- V as bf16 pairs: vpk[r] = {lo16: bf16 V[r][2*lane], hi16: bf16 V[r][2*lane+1]}
    //      unpack: lo -> (vpk<<16), hi -> (vpk & 0xffff0000) — pure bit-ops, f32 FMA pipe.
    unsigned vpk[RANK];
    #pragma unroll
    for (int r = 0; r < RANK; ++r) {
        const float2 v = reinterpret_cast<const float2*>(V + r * 128)[lane];
        vpk[r] = bf16_rne(v.x) | (bf16_rne(v.y) << 16);
    }
    const float2 b2 = reinterpret_cast<const float2*>(bias)[lane];

    float* hw = hbuf[wid];

    const int wave0 = blockIdx.x * WPB + wid;
    const int iters = (nrows + NWAVES - 1) / NWAVES;   // 32 at B=131072

    int row = wave0;
    // ---- prefetch row 0 (R4 shadow-buffer pattern: full-row distance) ----
    float x0n = 0.f, x1n = 0.f;
    float4 w4n[4] = {};
    if (row < nrows) {
        x0n = inp[row * 128 + lane];
        x1n = inp[row * 128 + 64 + lane];
        const float4* wp = reinterpret_cast<const float4*>(gw) + row * 256;
        #pragma unroll
        for (int t = 0; t < 4; ++t) w4n[t] = wp[t * 64 + lane];
    }

    for (int it = 0; it < iters; ++it) {
        if (row >= nrows) break;
        const float x0 = x0n, x1 = x1n;
        float4 w4[4];
        #pragma unroll
        for (int t = 0; t < 4; ++t) w4[t] = w4n[t];

        // ---- prefetch next row (overlaps with compute below) ----
        const int nrow = row + NWAVES;
        if (it + 1 < iters && nrow < nrows) {
            x0n = inp[nrow * 128 + lane];
            x1n = inp[nrow * 128 + 64 + lane];
            const float4* wp = reinterpret_cast<const float4*>(gw) + nrow * 256;
            #pragma unroll
            for (int t = 0; t < 4; ++t) w4n[t] = wp[t * 64 + lane];
        }

        // ---- step 1: h = inp_row @ U -------------------------------------
        // lane accumulates h[4c..4c+3] (c = lane&7) over i = t*8+g, t=0..15
        float h1a[4] = {0.f, 0.f, 0.f, 0.f};
        #pragma unroll
        for (int t = 0; t < 16; ++t) {
            const float xs = (t < 8) ? x0 : x1;            // t is constant
            const float xi = __shfl(xs, (t & 7) * 8 + g, 64);
            const float4 u = u4s[t * 64 + lane];
            h1a[0] = fmaf(xi, u.x, h1a[0]);
            h1a[1] = fmaf(xi, u.y, h1a[1]);
            h1a[2] = fmaf(xi, u.z, h1a[2]);
            h1a[3] = fmaf(xi, u.w, h1a[3]);
        }
        #pragma unroll
        for (int k = 0; k < 4; ++k) h1a[k] = red_g(h1a[k]);   // VALU butterfly
        // park h in per-wave LDS (lane group c holds h[4c..4c+3])
        if (lane < 8)
            reinterpret_cast<float4*>(hw)[lane] =
                make_float4(h1a[0], h1a[1], h1a[2], h1a[3]);

        // ---- step 2: h2 = h @ W_b ----------------------------------------
        float h2a[4] = {0.f, 0.f, 0.f, 0.f};
        #pragma unroll
        for (int t = 0; t < 4; ++t) {
            const float hi = hw[t * 8 + g];                // broadcast read
            h2a[0] = fmaf(hi, w4[t].x, h2a[0]);
            h2a[1] = fmaf(hi, w4[t].y, h2a[1]);
            h2a[2] = fmaf(hi, w4[t].z, h2a[2]);
            h2a[3] = fmaf(hi, w4[t].w, h2a[3]);
        }
        #pragma unroll
        for (int k = 0; k < 4; ++k) h2a[k] = red_g(h2a[k]);   // VALU butterfly

        // ---- step 3: out_row = h2 @ V + bias (readlane + bf16 unpack) ----
        float o0 = b2.x, o1 = b2.y;
        #pragma unroll
        for (int r = 0; r < RANK; ++r) {
            const float h2r = bcast(h2a[r & 3], r >> 2);
            const unsigned p = vpk[r];
            o0 = fmaf(h2r, __uint_as_float(p << 16),          o0);
            o1 = fmaf(h2r, __uint_as_float(p & 0xffff0000u),  o1);
        }
        reinterpret_cast<float2*>(out)[row * 64 + lane] = make_float2(o0, o1);

        row = nrow;
    }
}

extern "C" void kernel_launch(void* const* d_in, const int* in_sizes, int n_in,
                              void* d_out, int out_size, void* d_ws, size_t ws_size,
                              hipStream_t stream)
{
    const float* inp  = (const float*)d_in[0];
    const float* gw   = (const float*)d_in[1];
    const float* U    = (const float*)d_in[2];
    const float* V    = (const float*)d_in[3];
    const float* bias = (const float*)d_in[4];
    float* out = (float*)d_out;
    const int nrows = in_sizes[0] / 128;   // B = 131072

    apg_linear_kernel<<<GRID, BLOCK, 0, stream>>>(inp, gw, U, V, bias, out, nrows);
}